// Round 2
// baseline (3206.507 us; speedup 1.0000x reference)
//
#include <hip/hip_runtime.h>
#include <stdint.h>

typedef short bf16x8 __attribute__((ext_vector_type(8)));
typedef float f32x4 __attribute__((ext_vector_type(4)));

#define NROWS 50000
#define BATCH 32
#define SEQ 256
#define DIN 768
#define DMODEL 1024
#define NTOPK 5
#define DOTS_BLOCKS 250
#define ROWS_PER_IT 8
#define DOTS_ITERS 25   // 250 blocks * 8 rows * 25 iters = 50000

__device__ inline unsigned short f2bf(float f) {
  union { float f; unsigned u; } x; x.f = f;
  unsigned u = x.u;
  unsigned r = u + 0x7fffu + ((u >> 16) & 1u);
  return (unsigned short)(r >> 16);
}
__device__ inline float bf2f(unsigned short h) {
  union { unsigned u; float f; } x; x.u = ((unsigned)h) << 16; return x.f;
}

__device__ __forceinline__ void gl_lds16(const void* g, void* l) {
  __builtin_amdgcn_global_load_lds(
      (const __attribute__((address_space(1))) unsigned int*)g,
      (__attribute__((address_space(3))) unsigned int*)l, 16, 0, 0);
}

// ---------------- convert fp32 -> bf16 ----------------
__global__ void k_f32_to_bf16(const float* __restrict__ in, unsigned short* __restrict__ out, int n) {
  int i = (blockIdx.x * blockDim.x + threadIdx.x) * 4;
  int stride = gridDim.x * blockDim.x * 4;
  for (; i < n; i += stride) {
    float4 f = *(const float4*)(in + i);
    ushort4 o;
    o.x = f2bf(f.x); o.y = f2bf(f.y); o.z = f2bf(f.z); o.w = f2bf(f.w);
    *(ushort4*)(out + i) = o;
  }
}

// ---------------- mean over sequence ----------------
__global__ void k_mean_hidden(const float* __restrict__ hidden, float* __restrict__ hm) {
  int b = blockIdx.x;
  int i = threadIdx.x; // 768 threads
  const float* p = hidden + (size_t)b * SEQ * DIN + i;
  float s = 0.f;
  for (int t = 0; t < SEQ; ++t) s += p[t * DIN];
  hm[b * DIN + i] = s * (1.0f / SEQ);
}

// ---------------- small fp32 GEMM: C[M,N] = A[M,K] @ W[N,K]^T + beta*bias ----------------
__global__ void k_sgemm_wt(const float* __restrict__ A, const float* __restrict__ W,
                           const float* __restrict__ bias, float* __restrict__ C,
                           int M, int N, int K, float beta) {
  __shared__ float A_l[32][65];
  __shared__ float W_l[64][65];
  int tid = threadIdx.x;            // 256
  int tx = tid & 63, ty = tid >> 6; // ty = wave
  int n0 = blockIdx.x * 64, m0 = blockIdx.y * 32;
  float acc[8] = {0.f,0.f,0.f,0.f,0.f,0.f,0.f,0.f};
  for (int k0 = 0; k0 < K; k0 += 64) {
    #pragma unroll
    for (int i = 0; i < 8; ++i) {
      int idx = tid + 256 * i; int r = idx >> 6, c = idx & 63;
      A_l[r][c] = A[(size_t)(m0 + r) * K + k0 + c];
    }
    #pragma unroll
    for (int i = 0; i < 16; ++i) {
      int idx = tid + 256 * i; int r = idx >> 6, c = idx & 63;
      W_l[r][c] = W[(size_t)(n0 + r) * K + k0 + c];
    }
    __syncthreads();
    for (int kk = 0; kk < 64; ++kk) {
      float wv = W_l[tx][kk];
      #pragma unroll
      for (int r = 0; r < 8; ++r) acc[r] += A_l[ty * 8 + r][kk] * wv;
    }
    __syncthreads();
  }
  float bv = bias[n0 + tx] * beta;
  #pragma unroll
  for (int r = 0; r < 8; ++r) C[(size_t)(m0 + ty * 8 + r) * N + n0 + tx] = acc[r] + bv;
}

// ---------------- bf16 MFMA GEMM: C[M,N](bf16) = A[M,K]bf16 @ W[N,K]bf16^T + bias ----------------
__global__ __launch_bounds__(256) void k_bf16_gemm(const unsigned short* __restrict__ A,
    const unsigned short* __restrict__ W, const float* __restrict__ bias,
    unsigned short* __restrict__ C, int M, int N, int K) {
  __shared__ unsigned short As[128][32];
  __shared__ unsigned short Ws[128][32];
  int tid = threadIdx.x;
  int wave = tid >> 6, lane = tid & 63;
  int wr = wave >> 1, wc = wave & 1;
  int bm = blockIdx.y * 128, bn = blockIdx.x * 128;
  int srow = lane >> 2;        // 0..15
  int scol = (lane & 3) * 8;   // element offset within 32-elem k-slice
  f32x4 acc[4][4] = {};
  for (int k0 = 0; k0 < K; k0 += 32) {
    // async staging: each wave fills 32 rows of As and Ws (2 x 16 rows each)
    #pragma unroll
    for (int j = 0; j < 2; ++j) {
      int r0 = wave * 32 + j * 16;
      gl_lds16(A + (size_t)(bm + r0 + srow) * K + k0 + scol, &As[r0][0]);
      gl_lds16(W + (size_t)(bn + r0 + srow) * K + k0 + scol, &Ws[r0][0]);
    }
    __syncthreads();
    bf16x8 af[4], bfr[4];
    #pragma unroll
    for (int mi = 0; mi < 4; ++mi)
      af[mi] = *(const bf16x8*)(&As[wr * 64 + mi * 16 + (lane & 15)][(lane >> 4) * 8]);
    #pragma unroll
    for (int ni = 0; ni < 4; ++ni)
      bfr[ni] = *(const bf16x8*)(&Ws[wc * 64 + ni * 16 + (lane & 15)][(lane >> 4) * 8]);
    #pragma unroll
    for (int mi = 0; mi < 4; ++mi)
      #pragma unroll
      for (int ni = 0; ni < 4; ++ni)
        acc[mi][ni] = __builtin_amdgcn_mfma_f32_16x16x32_bf16(af[mi], bfr[ni], acc[mi][ni], 0, 0, 0);
    __syncthreads();
  }
  #pragma unroll
  for (int ni = 0; ni < 4; ++ni) {
    int col = bn + wc * 64 + ni * 16 + (lane & 15);
    float bv = bias[col];
    #pragma unroll
    for (int mi = 0; mi < 4; ++mi) {
      #pragma unroll
      for (int j = 0; j < 4; ++j) {
        int row = bm + wr * 64 + mi * 16 + (lane >> 4) * 4 + j;
        C[(size_t)row * N + col] = f2bf(acc[mi][ni][j] + bv);
      }
    }
  }
}

// ---------------- fused retrieval: dots + norms + per-block top-5 ----------------
// grid: 250 blocks x 1024 threads. Each block streams rows bid*8 + it*2000 + [0,8).
// Each thread handles 2 batches (bq, bq+16) x 16-float slice p.
// Output: candv/candi [250][32][5] per-block sorted top-5; pass1 also norm2[NROWS].
__global__ __launch_bounds__(1024) void k_dots(const float* __restrict__ table,
    const float* __restrict__ vecs, float* __restrict__ norm2g,
    float* __restrict__ candv, int* __restrict__ candi, int pass1) {
  __shared__ float red[2][16][ROWS_PER_IT][32];
  __shared__ float redn[2][16][ROWS_PER_IT];
  __shared__ float cand[2][ROWS_PER_IT][32];
  __shared__ float candn[2][ROWS_PER_IT];

  int tid = threadIdx.x;
  int wave = tid >> 6, lane = tid & 63;
  int bq = tid & 15;   // batch (also handles bq+16)
  int p  = tid >> 4;   // 0..63 k-slice of 16 floats

  float4 m0[4], m1[4];
  #pragma unroll
  for (int jj = 0; jj < 4; ++jj) {
    m0[jj] = *(const float4*)(vecs + bq * DMODEL + p * 16 + jj * 4);
    m1[jj] = *(const float4*)(vecs + (bq + 16) * DMODEL + p * 16 + jj * 4);
  }

  // running top-5 (meaningful on tid<32 only)
  float tv[5]; int ti[5];
  #pragma unroll
  for (int j = 0; j < 5; ++j) { tv[j] = -3.4e38f; ti[j] = 0x7fffffff; }

  int buf = 0;
  for (int it = 0; it < DOTS_ITERS; ++it) {
    int base = blockIdx.x * ROWS_PER_IT + it * (DOTS_BLOCKS * ROWS_PER_IT);
    float acc0[ROWS_PER_IT], acc1[ROWS_PER_IT], accn[ROWS_PER_IT];
    #pragma unroll
    for (int r = 0; r < ROWS_PER_IT; ++r) {
      const float* row = table + (size_t)(base + r) * DMODEL + p * 16;
      float a0 = 0.f, a1 = 0.f, an = 0.f;
      #pragma unroll
      for (int jj = 0; jj < 4; ++jj) {
        float4 f = *(const float4*)(row + jj * 4);
        a0 += f.x * m0[jj].x + f.y * m0[jj].y + f.z * m0[jj].z + f.w * m0[jj].w;
        a1 += f.x * m1[jj].x + f.y * m1[jj].y + f.z * m1[jj].z + f.w * m1[jj].w;
        if (pass1) an += f.x * f.x + f.y * f.y + f.z * f.z + f.w * f.w;
      }
      acc0[r] = a0; acc1[r] = a1; accn[r] = an;
    }
    #pragma unroll
    for (int r = 0; r < ROWS_PER_IT; ++r) {
      float a0 = acc0[r];
      a0 += __shfl_xor(a0, 16); a0 += __shfl_xor(a0, 32);
      float a1 = acc1[r];
      a1 += __shfl_xor(a1, 16); a1 += __shfl_xor(a1, 32);
      if (lane < 16) { red[buf][wave][r][lane] = a0; red[buf][wave][r][lane + 16] = a1; }
      if (pass1) {
        float an = accn[r];
        an += __shfl_xor(an, 16); an += __shfl_xor(an, 32);
        if (lane == 0) redn[buf][wave][r] = an;
      }
    }
    __syncthreads();
    if (tid < 256) {
      int r = tid >> 5, bb = tid & 31;
      float s = 0.f;
      #pragma unroll
      for (int w = 0; w < 16; ++w) s += red[buf][w][r][bb];
      cand[buf][r][bb] = s;
    } else if (tid < 256 + ROWS_PER_IT) {
      int r = tid - 256;
      float s;
      if (pass1) {
        s = 0.f;
        #pragma unroll
        for (int w = 0; w < 16; ++w) s += redn[buf][w][r];
        norm2g[base + r] = s;
      } else {
        s = norm2g[base + r];
      }
      candn[buf][r] = s;
    }
    // merge previous iteration's candidates (lags one iter; uses other buffer)
    if (tid < 32 && it > 0) {
      int pb = buf ^ 1;
      int pbase = base - DOTS_BLOCKS * ROWS_PER_IT;
      #pragma unroll
      for (int r = 0; r < ROWS_PER_IT; ++r) {
        float iv = 1.0f / fmaxf(sqrtf(candn[pb][r]), 1e-6f);
        float v = cand[pb][r][tid] * iv;
        int idx = pbase + r;
        if (v > tv[4] || (v == tv[4] && idx < ti[4])) {
          tv[4] = v; ti[4] = idx;
          #pragma unroll
          for (int j = 4; j > 0; --j) {
            bool sw = (tv[j] > tv[j-1]) || (tv[j] == tv[j-1] && ti[j] < ti[j-1]);
            if (sw) {
              float fv = tv[j]; tv[j] = tv[j-1]; tv[j-1] = fv;
              int ivx = ti[j]; ti[j] = ti[j-1]; ti[j-1] = ivx;
            }
          }
        }
      }
    }
    buf ^= 1;
  }
  // drain last iteration
  __syncthreads();
  if (tid < 32) {
    int pb = buf ^ 1;
    int pbase = blockIdx.x * ROWS_PER_IT + (DOTS_ITERS - 1) * (DOTS_BLOCKS * ROWS_PER_IT);
    #pragma unroll
    for (int r = 0; r < ROWS_PER_IT; ++r) {
      float iv = 1.0f / fmaxf(sqrtf(candn[pb][r]), 1e-6f);
      float v = cand[pb][r][tid] * iv;
      int idx = pbase + r;
      if (v > tv[4] || (v == tv[4] && idx < ti[4])) {
        tv[4] = v; ti[4] = idx;
        #pragma unroll
        for (int j = 4; j > 0; --j) {
          bool sw = (tv[j] > tv[j-1]) || (tv[j] == tv[j-1] && ti[j] < ti[j-1]);
          if (sw) {
            float fv = tv[j]; tv[j] = tv[j-1]; tv[j-1] = fv;
            int ivx = ti[j]; ti[j] = ti[j-1]; ti[j-1] = ivx;
          }
        }
      }
    }
    #pragma unroll
    for (int j = 0; j < 5; ++j) {
      candv[((size_t)blockIdx.x * 32 + tid) * 5 + j] = tv[j];
      candi[((size_t)blockIdx.x * 32 + tid) * 5 + j] = ti[j];
    }
  }
}

// ---------------- merge per-block candidates -> global top-K per batch ----------------
__global__ void k_merge(const float* __restrict__ candv, const int* __restrict__ candi,
                        int* __restrict__ out_idx, int K) {
  int b = blockIdx.x;
  int tid = threadIdx.x; // 256
  __shared__ float lv[256 * 5];
  __shared__ int   li[256 * 5];
  if (tid < DOTS_BLOCKS) {
    #pragma unroll
    for (int j = 0; j < 5; ++j) {
      lv[tid * 5 + j] = candv[((size_t)tid * 32 + b) * 5 + j];
      li[tid * 5 + j] = candi[((size_t)tid * 32 + b) * 5 + j];
    }
  } else {
    #pragma unroll
    for (int j = 0; j < 5; ++j) { lv[tid * 5 + j] = -3.4e38f; li[tid * 5 + j] = 0x7fffffff; }
  }
  __syncthreads();
  for (int off = 128; off >= 1; off >>= 1) {
    if (tid < off) {
      float av[5], bv[5]; int ai[5], bi[5];
      #pragma unroll
      for (int j = 0; j < 5; ++j) {
        av[j] = lv[tid * 5 + j]; ai[j] = li[tid * 5 + j];
        bv[j] = lv[(tid + off) * 5 + j]; bi[j] = li[(tid + off) * 5 + j];
      }
      int pa = 0, pb = 0;
      float mv[5]; int mi[5];
      #pragma unroll
      for (int j = 0; j < 5; ++j) {
        bool ta = (av[pa] > bv[pb]) || (av[pa] == bv[pb] && ai[pa] < bi[pb]);
        if (ta) { mv[j] = av[pa]; mi[j] = ai[pa]; ++pa; }
        else    { mv[j] = bv[pb]; mi[j] = bi[pb]; ++pb; }
      }
      #pragma unroll
      for (int j = 0; j < 5; ++j) { lv[tid * 5 + j] = mv[j]; li[tid * 5 + j] = mi[j]; }
    }
    __syncthreads();
  }
  if (tid == 0) {
    for (int j = 0; j < K; ++j) out_idx[b * K + j] = li[j];
  }
}

// ---------------- gathers ----------------
__global__ void k_gather_sel(const float* __restrict__ table, const int* __restrict__ best,
                             float* __restrict__ sel) {
  int b = blockIdx.x, e = threadIdx.x; // 1024
  int idx = best[b];
  sel[b * DMODEL + e] = table[(size_t)idx * DMODEL + e];
}

__global__ void k_gather_targets(const float* __restrict__ table, const int* __restrict__ idx5,
                                 float* __restrict__ tg) {
  int bt = blockIdx.x, e = threadIdx.x; // 1024
  int idx = idx5[bt];
  tg[(size_t)bt * DMODEL + e] = table[(size_t)idx * DMODEL + e];
}

// ---------------- attention: one block per (b, t) ----------------
__global__ __launch_bounds__(256) void k_attention(const float* __restrict__ q,
    const unsigned short* __restrict__ kb, const unsigned short* __restrict__ vb,
    float* __restrict__ obuf) {
  int bt = blockIdx.x;
  int b = bt / NTOPK;
  int tid = threadIdx.x; // 256
  __shared__ float q_l[DMODEL];
  __shared__ float sc[4][SEQ];
  #pragma unroll
  for (int j = 0; j < 4; ++j) q_l[tid + 256 * j] = q[(size_t)bt * DMODEL + tid + 256 * j];
  __syncthreads();
  { // scores: thread = key position s
    int s = tid;
    const unsigned short* krow = kb + ((size_t)(b * SEQ + s)) * DMODEL;
    #pragma unroll
    for (int h = 0; h < 4; ++h) {
      float d = 0.f;
      for (int dd = 0; dd < 256; dd += 8) {
        uint4 pk = *(const uint4*)(krow + h * 256 + dd);
        const unsigned short* ph = (const unsigned short*)&pk;
        #pragma unroll
        for (int j2 = 0; j2 < 8; ++j2) d += bf2f(ph[j2]) * q_l[h * 256 + dd + j2];
      }
      sc[h][s] = d * 0.0625f; // 1/sqrt(256)
    }
  }
  __syncthreads();
  { // softmax: wave w handles head h=w
    int h = tid >> 6, lane = tid & 63;
    float vals[4];
    float mx = -3.4e38f;
    #pragma unroll
    for (int j = 0; j < 4; ++j) { vals[j] = sc[h][lane + 64 * j]; mx = fmaxf(mx, vals[j]); }
    #pragma unroll
    for (int o = 1; o < 64; o <<= 1) mx = fmaxf(mx, __shfl_xor(mx, o));
    float sum = 0.f;
    #pragma unroll
    for (int j = 0; j < 4; ++j) { vals[j] = expf(vals[j] - mx); sum += vals[j]; }
    #pragma unroll
    for (int o = 1; o < 64; o <<= 1) sum += __shfl_xor(sum, o);
    float rz = 1.0f / sum;
    #pragma unroll
    for (int j = 0; j < 4; ++j) sc[h][lane + 64 * j] = vals[j] * rz;
  }
  __syncthreads();
  { // PV: thread owns 4 contiguous output dims
    int h = tid >> 6;
    int e0 = tid * 4;
    float a0 = 0.f, a1 = 0.f, a2 = 0.f, a3 = 0.f;
    const unsigned short* vbase = vb + (size_t)(b * SEQ) * DMODEL + e0;
    for (int s = 0; s < SEQ; ++s) {
      float w = sc[h][s];
      ushort4 v4 = *(const ushort4*)(vbase + (size_t)s * DMODEL);
      a0 += w * bf2f(v4.x); a1 += w * bf2f(v4.y); a2 += w * bf2f(v4.z); a3 += w * bf2f(v4.w);
    }
    float* op = obuf + (size_t)bt * DMODEL + e0;
    op[0] = a0; op[1] = a1; op[2] = a2; op[3] = a3;
  }
}

// ---------------- sum over the 5 queries ----------------
__global__ void k_osum(const float* __restrict__ obuf, float* __restrict__ osum) {
  int g = blockIdx.x * blockDim.x + threadIdx.x; // 32768
  if (g >= BATCH * DMODEL) return;
  int b = g >> 10, e = g & 1023;
  float s = 0.f;
  #pragma unroll
  for (int t = 0; t < NTOPK; ++t) s += obuf[(size_t)(b * NTOPK + t) * DMODEL + e];
  osum[g] = s;
}

extern "C" void kernel_launch(void* const* d_in, const int* in_sizes, int n_in,
                              void* d_out, int out_size, void* d_ws, size_t ws_size,
                              hipStream_t stream) {
  const float* hidden = (const float*)d_in[0];
  const float* table  = (const float*)d_in[1];
  const float* fc1_w  = (const float*)d_in[2];
  const float* fc1_b  = (const float*)d_in[3];
  const float* q_w    = (const float*)d_in[4];
  const float* q_b    = (const float*)d_in[5];
  const float* k_w    = (const float*)d_in[6];
  const float* k_b    = (const float*)d_in[7];
  const float* v_w    = (const float*)d_in[8];
  const float* v_b    = (const float*)d_in[9];
  const float* out_w  = (const float*)d_in[10];
  const float* out_b  = (const float*)d_in[11];
  float* out = (float*)d_out;

  char* ws = (char*)d_ws;
  size_t off = 0;
  auto alloc = [&](size_t bytes) -> void* {
    void* p = ws + off;
    off += (bytes + 255) & ~(size_t)255;
    return p;
  };
  unsigned short* hid_bf  = (unsigned short*)alloc((size_t)BATCH * SEQ * DIN * 2);
  unsigned short* fc1w_bf = (unsigned short*)alloc((size_t)DMODEL * DIN * 2);
  unsigned short* kw_bf   = (unsigned short*)alloc((size_t)DMODEL * DMODEL * 2);
  unsigned short* vw_bf   = (unsigned short*)alloc((size_t)DMODEL * DMODEL * 2);
  unsigned short* x_bf    = (unsigned short*)alloc((size_t)BATCH * SEQ * DMODEL * 2);
  unsigned short* k_bf    = (unsigned short*)alloc((size_t)BATCH * SEQ * DMODEL * 2);
  unsigned short* v_bf    = (unsigned short*)alloc((size_t)BATCH * SEQ * DMODEL * 2);
  float* hm      = (float*)alloc((size_t)BATCH * DIN * 4);
  float* m       = (float*)alloc((size_t)BATCH * DMODEL * 4);
  float* sel     = (float*)alloc((size_t)BATCH * DMODEL * 4);
  float* norm2   = (float*)alloc((size_t)NROWS * 4);
  float* candv   = (float*)alloc((size_t)DOTS_BLOCKS * 32 * 5 * 4);
  int*   candi   = (int*)alloc((size_t)DOTS_BLOCKS * 32 * 5 * 4);
  int*   best    = (int*)alloc(BATCH * 4);
  int*   idx5    = (int*)alloc(BATCH * NTOPK * 4);
  float* targets = (float*)alloc((size_t)BATCH * NTOPK * DMODEL * 4);
  float* qbuf    = (float*)alloc((size_t)BATCH * NTOPK * DMODEL * 4);
  float* obuf    = (float*)alloc((size_t)BATCH * NTOPK * DMODEL * 4);
  float* osum    = (float*)alloc((size_t)BATCH * DMODEL * 4);
  (void)ws_size; (void)in_sizes; (void)n_in; (void)out_size;

  // converts to bf16
  k_f32_to_bf16<<<2048, 256, 0, stream>>>(hidden, hid_bf, BATCH * SEQ * DIN);
  k_f32_to_bf16<<<768, 256, 0, stream>>>(fc1_w, fc1w_bf, DMODEL * DIN);
  k_f32_to_bf16<<<1024, 256, 0, stream>>>(k_w, kw_bf, DMODEL * DMODEL);
  k_f32_to_bf16<<<1024, 256, 0, stream>>>(v_w, vw_bf, DMODEL * DMODEL);

  // exact-fp32 mean path: m = mean_s(hidden) @ fc1_w^T + fc1_b
  k_mean_hidden<<<32, 768, 0, stream>>>(hidden, hm);
  k_sgemm_wt<<<dim3(16, 1), 256, 0, stream>>>(hm, fc1_w, fc1_b, m, 32, DMODEL, DIN, 1.0f);

  // fc1: x (bf16)
  k_bf16_gemm<<<dim3(8, 64), 256, 0, stream>>>(hid_bf, fc1w_bf, fc1_b, x_bf, BATCH * SEQ, DMODEL, DIN);

  // retrieval pass 1: cos argmax (fused dots+norms+per-block top5)
  k_dots<<<DOTS_BLOCKS, 1024, 0, stream>>>(table, m, norm2, candv, candi, 1);
  k_merge<<<32, 256, 0, stream>>>(candv, candi, best, 1);
  k_gather_sel<<<32, 1024, 0, stream>>>(table, best, sel);

  // retrieval pass 2: top-5 by dot(sel, t_i)/||t_i|| (ranking-equivalent to ref d2)
  k_dots<<<DOTS_BLOCKS, 1024, 0, stream>>>(table, sel, norm2, candv, candi, 0);
  k_merge<<<32, 256, 0, stream>>>(candv, candi, idx5, NTOPK);
  k_gather_targets<<<160, 1024, 0, stream>>>(table, idx5, targets);

  // q projection (fp32, small M)
  k_sgemm_wt<<<dim3(16, 5), 256, 0, stream>>>(targets, q_w, q_b, qbuf, BATCH * NTOPK, DMODEL, DMODEL, 1.0f);

  // k, v projections (bf16 MFMA)
  k_bf16_gemm<<<dim3(8, 64), 256, 0, stream>>>(x_bf, kw_bf, k_b, k_bf, BATCH * SEQ, DMODEL, DMODEL);
  k_bf16_gemm<<<dim3(8, 64), 256, 0, stream>>>(x_bf, vw_bf, v_b, v_bf, BATCH * SEQ, DMODEL, DMODEL);

  // attention + sum over queries + output projection
  k_attention<<<160, 256, 0, stream>>>(qbuf, k_bf, v_bf, obuf);
  k_osum<<<128, 256, 0, stream>>>(obuf, osum);
  k_sgemm_wt<<<dim3(16, 1), 256, 0, stream>>>(osum, out_w, out_b, out, 32, DMODEL, DMODEL, 5.0f);
}

// Round 3
// 711.725 us; speedup vs baseline: 4.5053x; 4.5053x over previous
//
#include <hip/hip_runtime.h>
#include <stdint.h>

typedef short bf16x8 __attribute__((ext_vector_type(8)));
typedef float f32x4 __attribute__((ext_vector_type(4)));

#define NROWS 50000
#define BATCH 32
#define SEQ 256
#define DIN 768
#define DMODEL 1024
#define NTOPK 5
#define DOTS_BLOCKS 782   // ceil(50000 / 64)

__device__ inline unsigned short f2bf(float f) {
  union { float f; unsigned u; } x; x.f = f;
  unsigned u = x.u;
  unsigned r = u + 0x7fffu + ((u >> 16) & 1u);
  return (unsigned short)(r >> 16);
}
__device__ inline float bf2f(unsigned short h) {
  union { unsigned u; float f; } x; x.u = ((unsigned)h) << 16; return x.f;
}

__device__ __forceinline__ void gl_lds16(const void* g, void* l) {
  __builtin_amdgcn_global_load_lds(
      (const __attribute__((address_space(1))) unsigned int*)g,
      (__attribute__((address_space(3))) unsigned int*)l, 16, 0, 0);
}

// ---------------- convert fp32 -> bf16 ----------------
__global__ void k_f32_to_bf16(const float* __restrict__ in, unsigned short* __restrict__ out, int n) {
  int i = (blockIdx.x * blockDim.x + threadIdx.x) * 4;
  int stride = gridDim.x * blockDim.x * 4;
  for (; i < n; i += stride) {
    float4 f = *(const float4*)(in + i);
    ushort4 o;
    o.x = f2bf(f.x); o.y = f2bf(f.y); o.z = f2bf(f.z); o.w = f2bf(f.w);
    *(ushort4*)(out + i) = o;
  }
}

// ---------------- mean over sequence ----------------
__global__ void k_mean_hidden(const float* __restrict__ hidden, float* __restrict__ hm) {
  int b = blockIdx.x;
  int i = threadIdx.x; // 768 threads
  const float* p = hidden + (size_t)b * SEQ * DIN + i;
  float s = 0.f;
  for (int t = 0; t < SEQ; ++t) s += p[t * DIN];
  hm[b * DIN + i] = s * (1.0f / SEQ);
}

// ---------------- small fp32 GEMM: C[M,N] = A[M,K] @ W[N,K]^T + beta*bias ----------------
__global__ void k_sgemm_wt(const float* __restrict__ A, const float* __restrict__ W,
                           const float* __restrict__ bias, float* __restrict__ C,
                           int M, int N, int K, float beta) {
  __shared__ float A_l[32][65];
  __shared__ float W_l[64][65];
  int tid = threadIdx.x;            // 256
  int tx = tid & 63, ty = tid >> 6; // ty = wave
  int n0 = blockIdx.x * 64, m0 = blockIdx.y * 32;
  float acc[8] = {0.f,0.f,0.f,0.f,0.f,0.f,0.f,0.f};
  for (int k0 = 0; k0 < K; k0 += 64) {
    #pragma unroll
    for (int i = 0; i < 8; ++i) {
      int idx = tid + 256 * i; int r = idx >> 6, c = idx & 63;
      A_l[r][c] = A[(size_t)(m0 + r) * K + k0 + c];
    }
    #pragma unroll
    for (int i = 0; i < 16; ++i) {
      int idx = tid + 256 * i; int r = idx >> 6, c = idx & 63;
      W_l[r][c] = W[(size_t)(n0 + r) * K + k0 + c];
    }
    __syncthreads();
    for (int kk = 0; kk < 64; ++kk) {
      float wv = W_l[tx][kk];
      #pragma unroll
      for (int r = 0; r < 8; ++r) acc[r] += A_l[ty * 8 + r][kk] * wv;
    }
    __syncthreads();
  }
  float bv = bias[n0 + tx] * beta;
  #pragma unroll
  for (int r = 0; r < 8; ++r) C[(size_t)(m0 + ty * 8 + r) * N + n0 + tx] = acc[r] + bv;
}

// ---------------- bf16 MFMA GEMM: C[M,N](bf16) = A[M,K]bf16 @ W[N,K]bf16^T + bias ----------------
__global__ __launch_bounds__(256) void k_bf16_gemm(const unsigned short* __restrict__ A,
    const unsigned short* __restrict__ W, const float* __restrict__ bias,
    unsigned short* __restrict__ C, int M, int N, int K) {
  __shared__ unsigned short As[128][32];
  __shared__ unsigned short Ws[128][32];
  int tid = threadIdx.x;
  int wave = tid >> 6, lane = tid & 63;
  int wr = wave >> 1, wc = wave & 1;
  int bm = blockIdx.y * 128, bn = blockIdx.x * 128;
  int srow = lane >> 2;        // 0..15
  int scol = (lane & 3) * 8;   // element offset within 32-elem k-slice
  f32x4 acc[4][4] = {};
  for (int k0 = 0; k0 < K; k0 += 32) {
    // async staging: each wave fills 32 rows of As and Ws (2 x 16 rows each)
    #pragma unroll
    for (int j = 0; j < 2; ++j) {
      int r0 = wave * 32 + j * 16;
      gl_lds16(A + (size_t)(bm + r0 + srow) * K + k0 + scol, &As[r0][0]);
      gl_lds16(W + (size_t)(bn + r0 + srow) * K + k0 + scol, &Ws[r0][0]);
    }
    __syncthreads();
    bf16x8 af[4], bfr[4];
    #pragma unroll
    for (int mi = 0; mi < 4; ++mi)
      af[mi] = *(const bf16x8*)(&As[wr * 64 + mi * 16 + (lane & 15)][(lane >> 4) * 8]);
    #pragma unroll
    for (int ni = 0; ni < 4; ++ni)
      bfr[ni] = *(const bf16x8*)(&Ws[wc * 64 + ni * 16 + (lane & 15)][(lane >> 4) * 8]);
    #pragma unroll
    for (int mi = 0; mi < 4; ++mi)
      #pragma unroll
      for (int ni = 0; ni < 4; ++ni)
        acc[mi][ni] = __builtin_amdgcn_mfma_f32_16x16x32_bf16(af[mi], bfr[ni], acc[mi][ni], 0, 0, 0);
    __syncthreads();
  }
  #pragma unroll
  for (int ni = 0; ni < 4; ++ni) {
    int col = bn + wc * 64 + ni * 16 + (lane & 15);
    float bv = bias[col];
    #pragma unroll
    for (int mi = 0; mi < 4; ++mi) {
      #pragma unroll
      for (int j = 0; j < 4; ++j) {
        int row = bm + wr * 64 + mi * 16 + (lane >> 4) * 4 + j;
        C[(size_t)row * N + col] = f2bf(acc[mi][ni][j] + bv);
      }
    }
  }
}

// ---------------- fused retrieval: lane-owns-row dots + norms + per-block top-5 ----------------
// grid: 782 blocks x 256 threads (4 waves). Block covers 64 rows (lane = row),
// wave w handles batches w*8 .. w*8+7. Query chunks are wave-uniform loads.
// Output: candv/candi [782][32][5]; pass1 also writes norm2g[NROWS].
__global__ __launch_bounds__(256, 4) void k_dots(const float* __restrict__ table,
    const float* __restrict__ vecs, float* __restrict__ norm2g,
    float* __restrict__ candv, int* __restrict__ candi, int pass1, float eps) {
  __shared__ float dot_lds[32][65];
  __shared__ float norm_lds[64];
  __shared__ float iv_lds[64];

  int tid = threadIdx.x;
  int wave = tid >> 6, lane = tid & 63;
  int row = blockIdx.x * 64 + lane;
  int rowc = row < NROWS ? row : NROWS - 1;

  int bq0 = __builtin_amdgcn_readfirstlane(wave * 8);
  const float* qbase = vecs + (size_t)bq0 * DMODEL;
  const float4* rp = (const float4*)(table + (size_t)rowc * DMODEL);

  float acc[8] = {0.f,0.f,0.f,0.f,0.f,0.f,0.f,0.f};
  float accn = 0.f;

  for (int e = 0; e < 64; ++e) {
    float4 c0 = rp[e * 4 + 0];
    float4 c1 = rp[e * 4 + 1];
    float4 c2 = rp[e * 4 + 2];
    float4 c3 = rp[e * 4 + 3];
    if (pass1 && wave == 0) {
      accn += c0.x*c0.x + c0.y*c0.y + c0.z*c0.z + c0.w*c0.w
            + c1.x*c1.x + c1.y*c1.y + c1.z*c1.z + c1.w*c1.w
            + c2.x*c2.x + c2.y*c2.y + c2.z*c2.z + c2.w*c2.w
            + c3.x*c3.x + c3.y*c3.y + c3.z*c3.z + c3.w*c3.w;
    }
    #pragma unroll
    for (int k = 0; k < 8; ++k) {
      const float4* qp = (const float4*)(qbase + (size_t)k * DMODEL + e * 16);
      float4 q0 = qp[0], q1 = qp[1], q2 = qp[2], q3 = qp[3];
      acc[k] += c0.x*q0.x + c0.y*q0.y + c0.z*q0.z + c0.w*q0.w
              + c1.x*q1.x + c1.y*q1.y + c1.z*q1.z + c1.w*q1.w
              + c2.x*q2.x + c2.y*q2.y + c2.z*q2.z + c2.w*q2.w
              + c3.x*q3.x + c3.y*q3.y + c3.z*q3.z + c3.w*q3.w;
    }
  }

  if (wave == 0) {
    float n2;
    if (pass1) {
      n2 = accn;
      if (row < NROWS) norm2g[row] = n2;
    } else {
      n2 = norm2g[rowc];
    }
    norm_lds[lane] = n2;
  }
  #pragma unroll
  for (int k = 0; k < 8; ++k) dot_lds[wave * 8 + k][lane] = acc[k];
  __syncthreads();
  if (tid < 64) iv_lds[tid] = 1.0f / fmaxf(sqrtf(norm_lds[tid]), eps);
  __syncthreads();

  if (tid < 32) {
    float tv[5]; int ti[5];
    #pragma unroll
    for (int j = 0; j < 5; ++j) { tv[j] = -3.4e38f; ti[j] = 0x7fffffff; }
    int rbase = blockIdx.x * 64;
    for (int r = 0; r < 64; ++r) {
      int rw = rbase + r;
      if (rw >= NROWS) break;
      float v = dot_lds[tid][r] * iv_lds[r];
      if (v > tv[4] || (v == tv[4] && rw < ti[4])) {
        tv[4] = v; ti[4] = rw;
        #pragma unroll
        for (int j = 4; j > 0; --j) {
          bool sw = (tv[j] > tv[j-1]) || (tv[j] == tv[j-1] && ti[j] < ti[j-1]);
          if (sw) {
            float fv = tv[j]; tv[j] = tv[j-1]; tv[j-1] = fv;
            int ivx = ti[j]; ti[j] = ti[j-1]; ti[j-1] = ivx;
          }
        }
      }
    }
    #pragma unroll
    for (int j = 0; j < 5; ++j) {
      candv[((size_t)blockIdx.x * 32 + tid) * 5 + j] = tv[j];
      candi[((size_t)blockIdx.x * 32 + tid) * 5 + j] = ti[j];
    }
  }
}

// ---------------- merge per-block candidates -> global top-K per batch ----------------
__global__ void k_merge(const float* __restrict__ candv, const int* __restrict__ candi,
                        int* __restrict__ out_idx, int K, int nblk) {
  int b = blockIdx.x;
  int tid = threadIdx.x; // 256
  float tv[5]; int ti[5];
  #pragma unroll
  for (int j = 0; j < 5; ++j) { tv[j] = -3.4e38f; ti[j] = 0x7fffffff; }
  for (int blk = tid; blk < nblk; blk += 256) {
    #pragma unroll
    for (int j = 0; j < 5; ++j) {
      float v = candv[((size_t)blk * 32 + b) * 5 + j];
      int idx = candi[((size_t)blk * 32 + b) * 5 + j];
      if (v > tv[4] || (v == tv[4] && idx < ti[4])) {
        tv[4] = v; ti[4] = idx;
        #pragma unroll
        for (int jj = 4; jj > 0; --jj) {
          bool sw = (tv[jj] > tv[jj-1]) || (tv[jj] == tv[jj-1] && ti[jj] < ti[jj-1]);
          if (sw) {
            float fv = tv[jj]; tv[jj] = tv[jj-1]; tv[jj-1] = fv;
            int ivx = ti[jj]; ti[jj] = ti[jj-1]; ti[jj-1] = ivx;
          }
        }
      }
    }
  }
  __shared__ float lv[256 * 5];
  __shared__ int   li[256 * 5];
  #pragma unroll
  for (int j = 0; j < 5; ++j) { lv[tid * 5 + j] = tv[j]; li[tid * 5 + j] = ti[j]; }
  __syncthreads();
  for (int off = 128; off >= 1; off >>= 1) {
    if (tid < off) {
      float av[5], bv[5]; int ai[5], bi[5];
      #pragma unroll
      for (int j = 0; j < 5; ++j) {
        av[j] = lv[tid * 5 + j]; ai[j] = li[tid * 5 + j];
        bv[j] = lv[(tid + off) * 5 + j]; bi[j] = li[(tid + off) * 5 + j];
      }
      int pa = 0, pb = 0;
      float mv[5]; int mi[5];
      #pragma unroll
      for (int j = 0; j < 5; ++j) {
        bool ta = (av[pa] > bv[pb]) || (av[pa] == bv[pb] && ai[pa] < bi[pb]);
        if (ta) { mv[j] = av[pa]; mi[j] = ai[pa]; ++pa; }
        else    { mv[j] = bv[pb]; mi[j] = bi[pb]; ++pb; }
      }
      #pragma unroll
      for (int j = 0; j < 5; ++j) { lv[tid * 5 + j] = mv[j]; li[tid * 5 + j] = mi[j]; }
    }
    __syncthreads();
  }
  if (tid == 0) {
    for (int j = 0; j < K; ++j) out_idx[b * K + j] = li[j];
  }
}

// ---------------- gathers ----------------
__global__ void k_gather_sel(const float* __restrict__ table, const int* __restrict__ best,
                             float* __restrict__ sel) {
  int b = blockIdx.x, e = threadIdx.x; // 1024
  int idx = best[b];
  sel[b * DMODEL + e] = table[(size_t)idx * DMODEL + e];
}

__global__ void k_gather_targets(const float* __restrict__ table, const int* __restrict__ idx5,
                                 float* __restrict__ tg) {
  int bt = blockIdx.x, e = threadIdx.x; // 1024
  int idx = idx5[bt];
  tg[(size_t)bt * DMODEL + e] = table[(size_t)idx * DMODEL + e];
}

// ---------------- attention: one block per (b, t) ----------------
__global__ __launch_bounds__(256) void k_attention(const float* __restrict__ q,
    const unsigned short* __restrict__ kb, const unsigned short* __restrict__ vb,
    float* __restrict__ obuf) {
  int bt = blockIdx.x;
  int b = bt / NTOPK;
  int tid = threadIdx.x; // 256
  __shared__ float q_l[DMODEL];
  __shared__ float sc[4][SEQ];
  #pragma unroll
  for (int j = 0; j < 4; ++j) q_l[tid + 256 * j] = q[(size_t)bt * DMODEL + tid + 256 * j];
  __syncthreads();
  { // scores: thread = key position s
    int s = tid;
    const unsigned short* krow = kb + ((size_t)(b * SEQ + s)) * DMODEL;
    #pragma unroll
    for (int h = 0; h < 4; ++h) {
      float d = 0.f;
      for (int dd = 0; dd < 256; dd += 8) {
        uint4 pk = *(const uint4*)(krow + h * 256 + dd);
        const unsigned short* ph = (const unsigned short*)&pk;
        #pragma unroll
        for (int j2 = 0; j2 < 8; ++j2) d += bf2f(ph[j2]) * q_l[h * 256 + dd + j2];
      }
      sc[h][s] = d * 0.0625f; // 1/sqrt(256)
    }
  }
  __syncthreads();
  { // softmax: wave w handles head h=w
    int h = tid >> 6, lane = tid & 63;
    float vals[4];
    float mx = -3.4e38f;
    #pragma unroll
    for (int j = 0; j < 4; ++j) { vals[j] = sc[h][lane + 64 * j]; mx = fmaxf(mx, vals[j]); }
    #pragma unroll
    for (int o = 1; o < 64; o <<= 1) mx = fmaxf(mx, __shfl_xor(mx, o));
    float sum = 0.f;
    #pragma unroll
    for (int j = 0; j < 4; ++j) { vals[j] = expf(vals[j] - mx); sum += vals[j]; }
    #pragma unroll
    for (int o = 1; o < 64; o <<= 1) sum += __shfl_xor(sum, o);
    float rz = 1.0f / sum;
    #pragma unroll
    for (int j = 0; j < 4; ++j) sc[h][lane + 64 * j] = vals[j] * rz;
  }
  __syncthreads();
  { // PV: thread owns 4 contiguous output dims
    int h = tid >> 6;
    int e0 = tid * 4;
    float a0 = 0.f, a1 = 0.f, a2 = 0.f, a3 = 0.f;
    const unsigned short* vbase = vb + (size_t)(b * SEQ) * DMODEL + e0;
    for (int s = 0; s < SEQ; ++s) {
      float w = sc[h][s];
      ushort4 v4 = *(const ushort4*)(vbase + (size_t)s * DMODEL);
      a0 += w * bf2f(v4.x); a1 += w * bf2f(v4.y); a2 += w * bf2f(v4.z); a3 += w * bf2f(v4.w);
    }
    float* op = obuf + (size_t)bt * DMODEL + e0;
    op[0] = a0; op[1] = a1; op[2] = a2; op[3] = a3;
  }
}

// ---------------- sum over the 5 queries ----------------
__global__ void k_osum(const float* __restrict__ obuf, float* __restrict__ osum) {
  int g = blockIdx.x * blockDim.x + threadIdx.x; // 32768
  if (g >= BATCH * DMODEL) return;
  int b = g >> 10, e = g & 1023;
  float s = 0.f;
  #pragma unroll
  for (int t = 0; t < NTOPK; ++t) s += obuf[(size_t)(b * NTOPK + t) * DMODEL + e];
  osum[g] = s;
}

extern "C" void kernel_launch(void* const* d_in, const int* in_sizes, int n_in,
                              void* d_out, int out_size, void* d_ws, size_t ws_size,
                              hipStream_t stream) {
  const float* hidden = (const float*)d_in[0];
  const float* table  = (const float*)d_in[1];
  const float* fc1_w  = (const float*)d_in[2];
  const float* fc1_b  = (const float*)d_in[3];
  const float* q_w    = (const float*)d_in[4];
  const float* q_b    = (const float*)d_in[5];
  const float* k_w    = (const float*)d_in[6];
  const float* k_b    = (const float*)d_in[7];
  const float* v_w    = (const float*)d_in[8];
  const float* v_b    = (const float*)d_in[9];
  const float* out_w  = (const float*)d_in[10];
  const float* out_b  = (const float*)d_in[11];
  float* out = (float*)d_out;

  char* ws = (char*)d_ws;
  size_t off = 0;
  auto alloc = [&](size_t bytes) -> void* {
    void* p = ws + off;
    off += (bytes + 255) & ~(size_t)255;
    return p;
  };
  unsigned short* hid_bf  = (unsigned short*)alloc((size_t)BATCH * SEQ * DIN * 2);
  unsigned short* fc1w_bf = (unsigned short*)alloc((size_t)DMODEL * DIN * 2);
  unsigned short* kw_bf   = (unsigned short*)alloc((size_t)DMODEL * DMODEL * 2);
  unsigned short* vw_bf   = (unsigned short*)alloc((size_t)DMODEL * DMODEL * 2);
  unsigned short* x_bf    = (unsigned short*)alloc((size_t)BATCH * SEQ * DMODEL * 2);
  unsigned short* k_bf    = (unsigned short*)alloc((size_t)BATCH * SEQ * DMODEL * 2);
  unsigned short* v_bf    = (unsigned short*)alloc((size_t)BATCH * SEQ * DMODEL * 2);
  float* hm      = (float*)alloc((size_t)BATCH * DIN * 4);
  float* m       = (float*)alloc((size_t)BATCH * DMODEL * 4);
  float* sel     = (float*)alloc((size_t)BATCH * DMODEL * 4);
  float* norm2   = (float*)alloc((size_t)NROWS * 4);
  float* candv   = (float*)alloc((size_t)DOTS_BLOCKS * 32 * 5 * 4);
  int*   candi   = (int*)alloc((size_t)DOTS_BLOCKS * 32 * 5 * 4);
  int*   best    = (int*)alloc(BATCH * 4);
  int*   idx5    = (int*)alloc(BATCH * NTOPK * 4);
  float* targets = (float*)alloc((size_t)BATCH * NTOPK * DMODEL * 4);
  float* qbuf    = (float*)alloc((size_t)BATCH * NTOPK * DMODEL * 4);
  float* obuf    = (float*)alloc((size_t)BATCH * NTOPK * DMODEL * 4);
  float* osum    = (float*)alloc((size_t)BATCH * DMODEL * 4);
  (void)ws_size; (void)in_sizes; (void)n_in; (void)out_size;

  // converts to bf16
  k_f32_to_bf16<<<2048, 256, 0, stream>>>(hidden, hid_bf, BATCH * SEQ * DIN);
  k_f32_to_bf16<<<768, 256, 0, stream>>>(fc1_w, fc1w_bf, DMODEL * DIN);
  k_f32_to_bf16<<<1024, 256, 0, stream>>>(k_w, kw_bf, DMODEL * DMODEL);
  k_f32_to_bf16<<<1024, 256, 0, stream>>>(v_w, vw_bf, DMODEL * DMODEL);

  // exact-fp32 mean path: m = mean_s(hidden) @ fc1_w^T + fc1_b
  k_mean_hidden<<<32, 768, 0, stream>>>(hidden, hm);
  k_sgemm_wt<<<dim3(16, 1), 256, 0, stream>>>(hm, fc1_w, fc1_b, m, 32, DMODEL, DIN, 1.0f);

  // fc1: x (bf16)
  k_bf16_gemm<<<dim3(8, 64), 256, 0, stream>>>(hid_bf, fc1w_bf, fc1_b, x_bf, BATCH * SEQ, DMODEL, DIN);

  // retrieval pass 1: cos argmax (lane-owns-row dots + norms + per-block top5)
  k_dots<<<DOTS_BLOCKS, 256, 0, stream>>>(table, m, norm2, candv, candi, 1, 1e-6f);
  k_merge<<<32, 256, 0, stream>>>(candv, candi, best, 1, DOTS_BLOCKS);
  k_gather_sel<<<32, 1024, 0, stream>>>(table, best, sel);

  // retrieval pass 2: top-5 by dot(sel, t_i)/||t_i|| (ranking-equivalent to ref d2)
  k_dots<<<DOTS_BLOCKS, 256, 0, stream>>>(table, sel, norm2, candv, candi, 0, 1e-12f);
  k_merge<<<32, 256, 0, stream>>>(candv, candi, idx5, NTOPK, DOTS_BLOCKS);
  k_gather_targets<<<160, 1024, 0, stream>>>(table, idx5, targets);

  // q projection (fp32, small M)
  k_sgemm_wt<<<dim3(16, 5), 256, 0, stream>>>(targets, q_w, q_b, qbuf, BATCH * NTOPK, DMODEL, DMODEL, 1.0f);

  // k, v projections (bf16 MFMA)
  k_bf16_gemm<<<dim3(8, 64), 256, 0, stream>>>(x_bf, kw_bf, k_b, k_bf, BATCH * SEQ, DMODEL, DMODEL);
  k_bf16_gemm<<<dim3(8, 64), 256, 0, stream>>>(x_bf, vw_bf, v_b, v_bf, BATCH * SEQ, DMODEL, DMODEL);

  // attention + sum over queries + output projection
  k_attention<<<160, 256, 0, stream>>>(qbuf, k_bf, v_bf, obuf);
  k_osum<<<128, 256, 0, stream>>>(obuf, osum);
  k_sgemm_wt<<<dim3(16, 1), 256, 0, stream>>>(osum, out_w, out_b, out, 32, DMODEL, DMODEL, 5.0f);
}

// Round 5
// 662.890 us; speedup vs baseline: 4.8372x; 1.0737x over previous
//
#include <hip/hip_runtime.h>
#include <stdint.h>

typedef short bf16x8 __attribute__((ext_vector_type(8)));
typedef float f32x4 __attribute__((ext_vector_type(4)));

#define NROWS 50000
#define BATCH 32
#define SEQ 256
#define DIN 768
#define DMODEL 1024
#define NTOPK 5
#define DOTS_BLOCKS 782   // ceil(50000 / 64)
#define TPITCH 68         // 64 + 4: keeps float4 rows 16B-aligned, spreads banks
#define CHUNK 64
#define NCHUNK (DMODEL / CHUNK)

__device__ inline unsigned short f2bf(float f) {
  union { float f; unsigned u; } x; x.f = f;
  unsigned u = x.u;
  unsigned r = u + 0x7fffu + ((u >> 16) & 1u);
  return (unsigned short)(r >> 16);
}
__device__ inline float bf2f(unsigned short h) {
  union { unsigned u; float f; } x; x.u = ((unsigned)h) << 16; return x.f;
}

__device__ __forceinline__ void gl_lds16(const void* g, void* l) {
  __builtin_amdgcn_global_load_lds(
      (const __attribute__((address_space(1))) unsigned int*)g,
      (__attribute__((address_space(3))) unsigned int*)l, 16, 0, 0);
}

// ---------------- convert fp32 -> bf16 ----------------
__global__ void k_f32_to_bf16(const float* __restrict__ in, unsigned short* __restrict__ out, int n) {
  int i = (blockIdx.x * blockDim.x + threadIdx.x) * 4;
  int stride = gridDim.x * blockDim.x * 4;
  for (; i < n; i += stride) {
    float4 f = *(const float4*)(in + i);
    ushort4 o;
    o.x = f2bf(f.x); o.y = f2bf(f.y); o.z = f2bf(f.z); o.w = f2bf(f.w);
    *(ushort4*)(out + i) = o;
  }
}

// ---------------- mean over sequence ----------------
__global__ void k_mean_hidden(const float* __restrict__ hidden, float* __restrict__ hm) {
  int b = blockIdx.x;
  int i = threadIdx.x; // 768 threads
  const float* p = hidden + (size_t)b * SEQ * DIN + i;
  float s = 0.f;
  for (int t = 0; t < SEQ; ++t) s += p[t * DIN];
  hm[b * DIN + i] = s * (1.0f / SEQ);
}

// ---------------- small fp32 GEMM: C[M,N] = A[M,K] @ W[N,K]^T + beta*bias ----------------
__global__ void k_sgemm_wt(const float* __restrict__ A, const float* __restrict__ W,
                           const float* __restrict__ bias, float* __restrict__ C,
                           int M, int N, int K, float beta) {
  __shared__ float A_l[32][65];
  __shared__ float W_l[64][65];
  int tid = threadIdx.x;            // 256
  int tx = tid & 63, ty = tid >> 6; // ty = wave
  int n0 = blockIdx.x * 64, m0 = blockIdx.y * 32;
  float acc[8] = {0.f,0.f,0.f,0.f,0.f,0.f,0.f,0.f};
  for (int k0 = 0; k0 < K; k0 += 64) {
    #pragma unroll
    for (int i = 0; i < 8; ++i) {
      int idx = tid + 256 * i; int r = idx >> 6, c = idx & 63;
      A_l[r][c] = A[(size_t)(m0 + r) * K + k0 + c];
    }
    #pragma unroll
    for (int i = 0; i < 16; ++i) {
      int idx = tid + 256 * i; int r = idx >> 6, c = idx & 63;
      W_l[r][c] = W[(size_t)(n0 + r) * K + k0 + c];
    }
    __syncthreads();
    for (int kk = 0; kk < 64; ++kk) {
      float wv = W_l[tx][kk];
      #pragma unroll
      for (int r = 0; r < 8; ++r) acc[r] += A_l[ty * 8 + r][kk] * wv;
    }
    __syncthreads();
  }
  float bv = bias[n0 + tx] * beta;
  #pragma unroll
  for (int r = 0; r < 8; ++r) C[(size_t)(m0 + ty * 8 + r) * N + n0 + tx] = acc[r] + bv;
}

// ---------------- bf16 MFMA GEMM: C[M,N](bf16) = A[M,K]bf16 @ W[N,K]bf16^T + bias ----------------
__global__ __launch_bounds__(256) void k_bf16_gemm(const unsigned short* __restrict__ A,
    const unsigned short* __restrict__ W, const float* __restrict__ bias,
    unsigned short* __restrict__ C, int M, int N, int K) {
  __shared__ unsigned short As[128][32];
  __shared__ unsigned short Ws[128][32];
  int tid = threadIdx.x;
  int wave = tid >> 6, lane = tid & 63;
  int wr = wave >> 1, wc = wave & 1;
  int bm = blockIdx.y * 128, bn = blockIdx.x * 128;
  int srow = lane >> 2;        // 0..15
  int scol = (lane & 3) * 8;   // element offset within 32-elem k-slice
  f32x4 acc[4][4] = {};
  for (int k0 = 0; k0 < K; k0 += 32) {
    // async staging: each wave fills 32 rows of As and Ws (2 x 16 rows each)
    #pragma unroll
    for (int j = 0; j < 2; ++j) {
      int r0 = wave * 32 + j * 16;
      gl_lds16(A + (size_t)(bm + r0 + srow) * K + k0 + scol, &As[r0][0]);
      gl_lds16(W + (size_t)(bn + r0 + srow) * K + k0 + scol, &Ws[r0][0]);
    }
    __syncthreads();
    bf16x8 af[4], bfr[4];
    #pragma unroll
    for (int mi = 0; mi < 4; ++mi)
      af[mi] = *(const bf16x8*)(&As[wr * 64 + mi * 16 + (lane & 15)][(lane >> 4) * 8]);
    #pragma unroll
    for (int ni = 0; ni < 4; ++ni)
      bfr[ni] = *(const bf16x8*)(&Ws[wc * 64 + ni * 16 + (lane & 15)][(lane >> 4) * 8]);
    #pragma unroll
    for (int mi = 0; mi < 4; ++mi)
      #pragma unroll
      for (int ni = 0; ni < 4; ++ni)
        acc[mi][ni] = __builtin_amdgcn_mfma_f32_16x16x32_bf16(af[mi], bfr[ni], acc[mi][ni], 0, 0, 0);
    __syncthreads();
  }
  #pragma unroll
  for (int ni = 0; ni < 4; ++ni) {
    int col = bn + wc * 64 + ni * 16 + (lane & 15);
    float bv = bias[col];
    #pragma unroll
    for (int mi = 0; mi < 4; ++mi) {
      #pragma unroll
      for (int j = 0; j < 4; ++j) {
        int row = bm + wr * 64 + mi * 16 + (lane >> 4) * 4 + j;
        C[(size_t)row * N + col] = f2bf(acc[mi][ni][j] + bv);
      }
    }
  }
}

// ---------------- fused retrieval v3: LDS-staged coalesced dots + norms + per-block top-5 ----
// grid: 782 blocks x 256 threads. Block covers 64 rows x 32 batches.
// K staged in 64-float chunks to LDS (coalesced); compute: lane = row, wave = 8 batches.
// Queries read via wave-uniform s_load. Output: candv/candi [782][32][5]; pass1 writes norm2g.
__global__ __launch_bounds__(256, 3) void k_dots(const float* __restrict__ table,
    const float* __restrict__ vecs, float* __restrict__ norm2g,
    float* __restrict__ candv, int* __restrict__ candi, int pass1, float eps) {
  __shared__ float t_lds[64 * TPITCH];
  __shared__ float dot_lds[32][65];
  __shared__ float norm_lds[64];
  __shared__ float iv_lds[64];

  int tid = threadIdx.x;
  int wave = tid >> 6, lane = tid & 63;
  int rbase = blockIdx.x * 64;

  // staging mapping: thread -> (row = tid>>2, quad group tid&3)
  int srow = tid >> 2;
  int sc4 = tid & 3;
  int grow = rbase + srow;
  if (grow >= NROWS) grow = NROWS - 1;
  const float* gsrc = table + (size_t)grow * DMODEL;

  int b0 = __builtin_amdgcn_readfirstlane(wave * 8);
  const float* qb = vecs + (size_t)b0 * DMODEL;

  float acc[8] = {0.f,0.f,0.f,0.f,0.f,0.f,0.f,0.f};
  float accn = 0.f;

  for (int ch = 0; ch < NCHUNK; ++ch) {
    int k0 = ch * CHUNK;
    __syncthreads();  // previous chunk's readers done before overwrite
    #pragma unroll
    for (int i = 0; i < 4; ++i) {
      int c4 = sc4 + i * 4;
      float4 v = *(const float4*)(gsrc + k0 + c4 * 4);
      *(float4*)(&t_lds[srow * TPITCH + c4 * 4]) = v;
    }
    __syncthreads();
    #pragma unroll 2
    for (int q4 = 0; q4 < 16; ++q4) {
      float4 tv = *(const float4*)(&t_lds[lane * TPITCH + q4 * 4]);
      if (pass1 && wave == 0)
        accn += tv.x * tv.x + tv.y * tv.y + tv.z * tv.z + tv.w * tv.w;
      #pragma unroll
      for (int j = 0; j < 8; ++j) {
        float4 qv = *(const float4*)(qb + (size_t)j * DMODEL + k0 + q4 * 4);
        acc[j] += tv.x * qv.x + tv.y * qv.y + tv.z * qv.z + tv.w * qv.w;
      }
    }
  }

  __syncthreads();
  #pragma unroll
  for (int j = 0; j < 8; ++j) dot_lds[wave * 8 + j][lane] = acc[j];
  if (wave == 0 && pass1) {
    norm_lds[lane] = accn;
    int rw = rbase + lane;
    if (rw < NROWS) norm2g[rw] = accn;
  }
  __syncthreads();
  if (tid < 64) {
    int rc = rbase + tid;
    if (rc >= NROWS) rc = NROWS - 1;
    float n2 = pass1 ? norm_lds[tid] : norm2g[rc];
    iv_lds[tid] = 1.0f / fmaxf(sqrtf(n2), eps);
  }
  __syncthreads();

  if (tid < 32) {
    float tv[5]; int ti[5];
    #pragma unroll
    for (int j = 0; j < 5; ++j) { tv[j] = -3.4e38f; ti[j] = 0x7fffffff; }
    for (int r = 0; r < 64; ++r) {
      int rw = rbase + r;
      if (rw >= NROWS) break;
      float v = dot_lds[tid][r] * iv_lds[r];
      if (v > tv[4] || (v == tv[4] && rw < ti[4])) {
        tv[4] = v; ti[4] = rw;
        #pragma unroll
        for (int j = 4; j > 0; --j) {
          bool sw = (tv[j] > tv[j-1]) || (tv[j] == tv[j-1] && ti[j] < ti[j-1]);
          if (sw) {
            float fv = tv[j]; tv[j] = tv[j-1]; tv[j-1] = fv;
            int ivx = ti[j]; ti[j] = ti[j-1]; ti[j-1] = ivx;
          }
        }
      }
    }
    #pragma unroll
    for (int j = 0; j < 5; ++j) {
      candv[((size_t)blockIdx.x * 32 + tid) * 5 + j] = tv[j];
      candi[((size_t)blockIdx.x * 32 + tid) * 5 + j] = ti[j];
    }
  }
}

// ---------------- merge per-block candidates -> global top-K per batch ----------------
__global__ void k_merge(const float* __restrict__ candv, const int* __restrict__ candi,
                        int* __restrict__ out_idx, int K, int nblk) {
  int b = blockIdx.x;
  int tid = threadIdx.x; // 256
  float tv[5]; int ti[5];
  #pragma unroll
  for (int j = 0; j < 5; ++j) { tv[j] = -3.4e38f; ti[j] = 0x7fffffff; }
  for (int blk = tid; blk < nblk; blk += 256) {
    #pragma unroll
    for (int j = 0; j < 5; ++j) {
      float v = candv[((size_t)blk * 32 + b) * 5 + j];
      int idx = candi[((size_t)blk * 32 + b) * 5 + j];
      if (v > tv[4] || (v == tv[4] && idx < ti[4])) {
        tv[4] = v; ti[4] = idx;
        #pragma unroll
        for (int jj = 4; jj > 0; --jj) {
          bool sw = (tv[jj] > tv[jj-1]) || (tv[jj] == tv[jj-1] && ti[jj] < ti[jj-1]);
          if (sw) {
            float fv = tv[jj]; tv[jj] = tv[jj-1]; tv[jj-1] = fv;
            int ivx = ti[jj]; ti[jj] = ti[jj-1]; ti[jj-1] = ivx;
          }
        }
      }
    }
  }
  __shared__ float lv[256 * 5];
  __shared__ int   li[256 * 5];
  #pragma unroll
  for (int j = 0; j < 5; ++j) { lv[tid * 5 + j] = tv[j]; li[tid * 5 + j] = ti[j]; }
  __syncthreads();
  for (int off = 128; off >= 1; off >>= 1) {
    if (tid < off) {
      float av[5], bv[5]; int ai[5], bi[5];
      #pragma unroll
      for (int j = 0; j < 5; ++j) {
        av[j] = lv[tid * 5 + j]; ai[j] = li[tid * 5 + j];
        bv[j] = lv[(tid + off) * 5 + j]; bi[j] = li[(tid + off) * 5 + j];
      }
      int pa = 0, pb = 0;
      float mv[5]; int mi[5];
      #pragma unroll
      for (int j = 0; j < 5; ++j) {
        bool ta = (av[pa] > bv[pb]) || (av[pa] == bv[pb] && ai[pa] < bi[pb]);
        if (ta) { mv[j] = av[pa]; mi[j] = ai[pa]; ++pa; }
        else    { mv[j] = bv[pb]; mi[j] = bi[pb]; ++pb; }
      }
      #pragma unroll
      for (int j = 0; j < 5; ++j) { lv[tid * 5 + j] = mv[j]; li[tid * 5 + j] = mi[j]; }
    }
    __syncthreads();
  }
  if (tid == 0) {
    for (int j = 0; j < K; ++j) out_idx[b * K + j] = li[j];
  }
}

// ---------------- gathers ----------------
__global__ void k_gather_sel(const float* __restrict__ table, const int* __restrict__ best,
                             float* __restrict__ sel) {
  int b = blockIdx.x, e = threadIdx.x; // 1024
  int idx = best[b];
  sel[b * DMODEL + e] = table[(size_t)idx * DMODEL + e];
}

__global__ void k_gather_targets(const float* __restrict__ table, const int* __restrict__ idx5,
                                 float* __restrict__ tg) {
  int bt = blockIdx.x, e = threadIdx.x; // 1024
  int idx = idx5[bt];
  tg[(size_t)bt * DMODEL + e] = table[(size_t)idx * DMODEL + e];
}

// ---------------- attention: one block per (b, t) ----------------
__global__ __launch_bounds__(256) void k_attention(const float* __restrict__ q,
    const unsigned short* __restrict__ kb, const unsigned short* __restrict__ vb,
    float* __restrict__ obuf) {
  int bt = blockIdx.x;
  int b = bt / NTOPK;
  int tid = threadIdx.x; // 256
  __shared__ float q_l[DMODEL];
  __shared__ float sc[4][SEQ];
  #pragma unroll
  for (int j = 0; j < 4; ++j) q_l[tid + 256 * j] = q[(size_t)bt * DMODEL + tid + 256 * j];
  __syncthreads();
  { // scores: thread = key position s
    int s = tid;
    const unsigned short* krow = kb + ((size_t)(b * SEQ + s)) * DMODEL;
    #pragma unroll
    for (int h = 0; h < 4; ++h) {
      float d = 0.f;
      for (int dd = 0; dd < 256; dd += 8) {
        uint4 pk = *(const uint4*)(krow + h * 256 + dd);
        const unsigned short* ph = (const unsigned short*)&pk;
        #pragma unroll
        for (int j2 = 0; j2 < 8; ++j2) d += bf2f(ph[j2]) * q_l[h * 256 + dd + j2];
      }
      sc[h][s] = d * 0.0625f; // 1/sqrt(256)
    }
  }
  __syncthreads();
  { // softmax: wave w handles head h=w
    int h = tid >> 6, lane = tid & 63;
    float vals[4];
    float mx = -3.4e38f;
    #pragma unroll
    for (int j = 0; j < 4; ++j) { vals[j] = sc[h][lane + 64 * j]; mx = fmaxf(mx, vals[j]); }
    #pragma unroll
    for (int o = 1; o < 64; o <<= 1) mx = fmaxf(mx, __shfl_xor(mx, o));
    float sum = 0.f;
    #pragma unroll
    for (int j = 0; j < 4; ++j) { vals[j] = expf(vals[j] - mx); sum += vals[j]; }
    #pragma unroll
    for (int o = 1; o < 64; o <<= 1) sum += __shfl_xor(sum, o);
    float rz = 1.0f / sum;
    #pragma unroll
    for (int j = 0; j < 4; ++j) sc[h][lane + 64 * j] = vals[j] * rz;
  }
  __syncthreads();
  { // PV: thread owns 4 contiguous output dims
    int h = tid >> 6;
    int e0 = tid * 4;
    float a0 = 0.f, a1 = 0.f, a2 = 0.f, a3 = 0.f;
    const unsigned short* vbase = vb + (size_t)(b * SEQ) * DMODEL + e0;
    for (int s = 0; s < SEQ; ++s) {
      float w = sc[h][s];
      ushort4 v4 = *(const ushort4*)(vbase + (size_t)s * DMODEL);
      a0 += w * bf2f(v4.x); a1 += w * bf2f(v4.y); a2 += w * bf2f(v4.z); a3 += w * bf2f(v4.w);
    }
    float* op = obuf + (size_t)bt * DMODEL + e0;
    op[0] = a0; op[1] = a1; op[2] = a2; op[3] = a3;
  }
}

// ---------------- sum over the 5 queries ----------------
__global__ void k_osum(const float* __restrict__ obuf, float* __restrict__ osum) {
  int g = blockIdx.x * blockDim.x + threadIdx.x; // 32768
  if (g >= BATCH * DMODEL) return;
  int b = g >> 10, e = g & 1023;
  float s = 0.f;
  #pragma unroll
  for (int t = 0; t < NTOPK; ++t) s += obuf[(size_t)(b * NTOPK + t) * DMODEL + e];
  osum[g] = s;
}

extern "C" void kernel_launch(void* const* d_in, const int* in_sizes, int n_in,
                              void* d_out, int out_size, void* d_ws, size_t ws_size,
                              hipStream_t stream) {
  const float* hidden = (const float*)d_in[0];
  const float* table  = (const float*)d_in[1];
  const float* fc1_w  = (const float*)d_in[2];
  const float* fc1_b  = (const float*)d_in[3];
  const float* q_w    = (const float*)d_in[4];
  const float* q_b    = (const float*)d_in[5];
  const float* k_w    = (const float*)d_in[6];
  const float* k_b    = (const float*)d_in[7];
  const float* v_w    = (const float*)d_in[8];
  const float* v_b    = (const float*)d_in[9];
  const float* out_w  = (const float*)d_in[10];
  const float* out_b  = (const float*)d_in[11];
  float* out = (float*)d_out;

  char* ws = (char*)d_ws;
  size_t off = 0;
  auto alloc = [&](size_t bytes) -> void* {
    void* p = ws + off;
    off += (bytes + 255) & ~(size_t)255;
    return p;
  };
  unsigned short* hid_bf  = (unsigned short*)alloc((size_t)BATCH * SEQ * DIN * 2);
  unsigned short* fc1w_bf = (unsigned short*)alloc((size_t)DMODEL * DIN * 2);
  unsigned short* kw_bf   = (unsigned short*)alloc((size_t)DMODEL * DMODEL * 2);
  unsigned short* vw_bf   = (unsigned short*)alloc((size_t)DMODEL * DMODEL * 2);
  unsigned short* x_bf    = (unsigned short*)alloc((size_t)BATCH * SEQ * DMODEL * 2);
  unsigned short* k_bf    = (unsigned short*)alloc((size_t)BATCH * SEQ * DMODEL * 2);
  unsigned short* v_bf    = (unsigned short*)alloc((size_t)BATCH * SEQ * DMODEL * 2);
  float* hm      = (float*)alloc((size_t)BATCH * DIN * 4);
  float* m       = (float*)alloc((size_t)BATCH * DMODEL * 4);
  float* sel     = (float*)alloc((size_t)BATCH * DMODEL * 4);
  float* norm2   = (float*)alloc((size_t)NROWS * 4);
  float* candv   = (float*)alloc((size_t)DOTS_BLOCKS * 32 * 5 * 4);
  int*   candi   = (int*)alloc((size_t)DOTS_BLOCKS * 32 * 5 * 4);
  int*   best    = (int*)alloc(BATCH * 4);
  int*   idx5    = (int*)alloc(BATCH * NTOPK * 4);
  float* targets = (float*)alloc((size_t)BATCH * NTOPK * DMODEL * 4);
  float* qbuf    = (float*)alloc((size_t)BATCH * NTOPK * DMODEL * 4);
  float* obuf    = (float*)alloc((size_t)BATCH * NTOPK * DMODEL * 4);
  float* osum    = (float*)alloc((size_t)BATCH * DMODEL * 4);
  (void)ws_size; (void)in_sizes; (void)n_in; (void)out_size;

  // converts to bf16
  k_f32_to_bf16<<<2048, 256, 0, stream>>>(hidden, hid_bf, BATCH * SEQ * DIN);
  k_f32_to_bf16<<<768, 256, 0, stream>>>(fc1_w, fc1w_bf, DMODEL * DIN);
  k_f32_to_bf16<<<1024, 256, 0, stream>>>(k_w, kw_bf, DMODEL * DMODEL);
  k_f32_to_bf16<<<1024, 256, 0, stream>>>(v_w, vw_bf, DMODEL * DMODEL);

  // exact-fp32 mean path: m = mean_s(hidden) @ fc1_w^T + fc1_b
  k_mean_hidden<<<32, 768, 0, stream>>>(hidden, hm);
  k_sgemm_wt<<<dim3(16, 1), 256, 0, stream>>>(hm, fc1_w, fc1_b, m, 32, DMODEL, DIN, 1.0f);

  // fc1: x (bf16)
  k_bf16_gemm<<<dim3(8, 64), 256, 0, stream>>>(hid_bf, fc1w_bf, fc1_b, x_bf, BATCH * SEQ, DMODEL, DIN);

  // retrieval pass 1: cos argmax (LDS-staged coalesced dots + norms + per-block top5)
  k_dots<<<DOTS_BLOCKS, 256, 0, stream>>>(table, m, norm2, candv, candi, 1, 1e-6f);
  k_merge<<<32, 256, 0, stream>>>(candv, candi, best, 1, DOTS_BLOCKS);
  k_gather_sel<<<32, 1024, 0, stream>>>(table, best, sel);

  // retrieval pass 2: top-5 by dot(sel, t_i)/||t_i|| (ranking-equivalent to ref d2)
  k_dots<<<DOTS_BLOCKS, 256, 0, stream>>>(table, sel, norm2, candv, candi, 0, 1e-12f);
  k_merge<<<32, 256, 0, stream>>>(candv, candi, idx5, NTOPK, DOTS_BLOCKS);
  k_gather_targets<<<160, 1024, 0, stream>>>(table, idx5, targets);

  // q projection (fp32, small M)
  k_sgemm_wt<<<dim3(16, 5), 256, 0, stream>>>(targets, q_w, q_b, qbuf, BATCH * NTOPK, DMODEL, DMODEL, 1.0f);

  // k, v projections (bf16 MFMA)
  k_bf16_gemm<<<dim3(8, 64), 256, 0, stream>>>(x_bf, kw_bf, k_b, k_bf, BATCH * SEQ, DMODEL, DMODEL);
  k_bf16_gemm<<<dim3(8, 64), 256, 0, stream>>>(x_bf, vw_bf, v_b, v_bf, BATCH * SEQ, DMODEL, DMODEL);

  // attention + sum over queries + output projection
  k_attention<<<160, 256, 0, stream>>>(qbuf, k_bf, v_bf, obuf);
  k_osum<<<128, 256, 0, stream>>>(obuf, osum);
  k_sgemm_wt<<<dim3(16, 1), 256, 0, stream>>>(osum, out_w, out_b, out, 32, DMODEL, DMODEL, 5.0f);
}

// Round 6
// 644.164 us; speedup vs baseline: 4.9778x; 1.0291x over previous
//
#include <hip/hip_runtime.h>
#include <stdint.h>

typedef short bf16x8 __attribute__((ext_vector_type(8)));
typedef float f32x4 __attribute__((ext_vector_type(4)));

#define NROWS 50000
#define BATCH 32
#define SEQ 256
#define DIN 768
#define DMODEL 1024
#define NTOPK 5
#define DOTS_BLOCKS 782   // ceil(50000 / 64)
#define CHUNKF 64         // floats per chunk per row
#define NCHUNK (DMODEL / CHUNKF)

__device__ inline unsigned short f2bf(float f) {
  union { float f; unsigned u; } x; x.f = f;
  unsigned u = x.u;
  unsigned r = u + 0x7fffu + ((u >> 16) & 1u);
  return (unsigned short)(r >> 16);
}
__device__ inline float bf2f(unsigned short h) {
  union { unsigned u; float f; } x; x.u = ((unsigned)h) << 16; return x.f;
}

__device__ __forceinline__ void gl_lds16(const void* g, void* l) {
  __builtin_amdgcn_global_load_lds(
      (const __attribute__((address_space(1))) unsigned int*)g,
      (__attribute__((address_space(3))) unsigned int*)l, 16, 0, 0);
}

// ---------------- convert fp32 -> bf16 ----------------
__global__ void k_f32_to_bf16(const float* __restrict__ in, unsigned short* __restrict__ out, int n) {
  int i = (blockIdx.x * blockDim.x + threadIdx.x) * 4;
  int stride = gridDim.x * blockDim.x * 4;
  for (; i < n; i += stride) {
    float4 f = *(const float4*)(in + i);
    ushort4 o;
    o.x = f2bf(f.x); o.y = f2bf(f.y); o.z = f2bf(f.z); o.w = f2bf(f.w);
    *(ushort4*)(out + i) = o;
  }
}

// three tensors in one launch
__global__ void k_f32_to_bf16_3(const float* __restrict__ i0, unsigned short* __restrict__ o0, int n0,
                                const float* __restrict__ i1, unsigned short* __restrict__ o1, int n1,
                                const float* __restrict__ i2, unsigned short* __restrict__ o2, int n2) {
  int base = (blockIdx.x * blockDim.x + threadIdx.x) * 4;
  int stride = gridDim.x * blockDim.x * 4;
  for (int i = base; i < n0; i += stride) {
    float4 f = *(const float4*)(i0 + i);
    ushort4 o; o.x = f2bf(f.x); o.y = f2bf(f.y); o.z = f2bf(f.z); o.w = f2bf(f.w);
    *(ushort4*)(o0 + i) = o;
  }
  for (int i = base; i < n1; i += stride) {
    float4 f = *(const float4*)(i1 + i);
    ushort4 o; o.x = f2bf(f.x); o.y = f2bf(f.y); o.z = f2bf(f.z); o.w = f2bf(f.w);
    *(ushort4*)(o1 + i) = o;
  }
  for (int i = base; i < n2; i += stride) {
    float4 f = *(const float4*)(i2 + i);
    ushort4 o; o.x = f2bf(f.x); o.y = f2bf(f.y); o.z = f2bf(f.z); o.w = f2bf(f.w);
    *(ushort4*)(o2 + i) = o;
  }
}

// ---------------- mean over sequence: 2-stage ----------------
__global__ void k_mean_part(const float* __restrict__ hidden, float* __restrict__ hpart) {
  int b = blockIdx.x >> 3, tc = blockIdx.x & 7;   // 256 blocks
  int i = threadIdx.x;                            // 768
  const float* p = hidden + ((size_t)b * SEQ + tc * 32) * DIN + i;
  float s = 0.f;
  #pragma unroll 4
  for (int t = 0; t < 32; ++t) s += p[t * DIN];
  hpart[((size_t)tc * 32 + b) * DIN + i] = s;
}
__global__ void k_mean_reduce(const float* __restrict__ hpart, float* __restrict__ hm) {
  int b = blockIdx.x;          // 32
  int i = threadIdx.x;         // 768
  float s = 0.f;
  #pragma unroll
  for (int tc = 0; tc < 8; ++tc) s += hpart[((size_t)tc * 32 + b) * DIN + i];
  hm[b * DIN + i] = s * (1.0f / SEQ);
}

// ---------------- small fp32 GEMM: C[M,N] = A[M,K] @ W[N,K]^T + beta*bias ----------------
__global__ void k_sgemm_wt(const float* __restrict__ A, const float* __restrict__ W,
                           const float* __restrict__ bias, float* __restrict__ C,
                           int M, int N, int K, float beta) {
  __shared__ float A_l[32][65];
  __shared__ float W_l[64][65];
  int tid = threadIdx.x;            // 256
  int tx = tid & 63, ty = tid >> 6; // ty = wave
  int n0 = blockIdx.x * 64, m0 = blockIdx.y * 32;
  float acc[8] = {0.f,0.f,0.f,0.f,0.f,0.f,0.f,0.f};
  for (int k0 = 0; k0 < K; k0 += 64) {
    #pragma unroll
    for (int i = 0; i < 8; ++i) {
      int idx = tid + 256 * i; int r = idx >> 6, c = idx & 63;
      A_l[r][c] = A[(size_t)(m0 + r) * K + k0 + c];
    }
    #pragma unroll
    for (int i = 0; i < 16; ++i) {
      int idx = tid + 256 * i; int r = idx >> 6, c = idx & 63;
      W_l[r][c] = W[(size_t)(n0 + r) * K + k0 + c];
    }
    __syncthreads();
    for (int kk = 0; kk < 64; ++kk) {
      float wv = W_l[tx][kk];
      #pragma unroll
      for (int r = 0; r < 8; ++r) acc[r] += A_l[ty * 8 + r][kk] * wv;
    }
    __syncthreads();
  }
  float bv = bias[n0 + tx] * beta;
  #pragma unroll
  for (int r = 0; r < 8; ++r) C[(size_t)(m0 + ty * 8 + r) * N + n0 + tx] = acc[r] + bv;
}

// ---------------- bf16 MFMA GEMM: C[M,N](bf16) = A[M,K]bf16 @ W[N,K]bf16^T + bias ----------------
__global__ __launch_bounds__(256) void k_bf16_gemm(const unsigned short* __restrict__ A,
    const unsigned short* __restrict__ W, const float* __restrict__ bias,
    unsigned short* __restrict__ C, int M, int N, int K) {
  __shared__ unsigned short As[128][32];
  __shared__ unsigned short Ws[128][32];
  int tid = threadIdx.x;
  int wave = tid >> 6, lane = tid & 63;
  int wr = wave >> 1, wc = wave & 1;
  int bm = blockIdx.y * 128, bn = blockIdx.x * 128;
  int srow = lane >> 2;        // 0..15
  int scol = (lane & 3) * 8;   // element offset within 32-elem k-slice
  f32x4 acc[4][4] = {};
  for (int k0 = 0; k0 < K; k0 += 32) {
    #pragma unroll
    for (int j = 0; j < 2; ++j) {
      int r0 = wave * 32 + j * 16;
      gl_lds16(A + (size_t)(bm + r0 + srow) * K + k0 + scol, &As[r0][0]);
      gl_lds16(W + (size_t)(bn + r0 + srow) * K + k0 + scol, &Ws[r0][0]);
    }
    __syncthreads();
    bf16x8 af[4], bfr[4];
    #pragma unroll
    for (int mi = 0; mi < 4; ++mi)
      af[mi] = *(const bf16x8*)(&As[wr * 64 + mi * 16 + (lane & 15)][(lane >> 4) * 8]);
    #pragma unroll
    for (int ni = 0; ni < 4; ++ni)
      bfr[ni] = *(const bf16x8*)(&Ws[wc * 64 + ni * 16 + (lane & 15)][(lane >> 4) * 8]);
    #pragma unroll
    for (int mi = 0; mi < 4; ++mi)
      #pragma unroll
      for (int ni = 0; ni < 4; ++ni)
        acc[mi][ni] = __builtin_amdgcn_mfma_f32_16x16x32_bf16(af[mi], bfr[ni], acc[mi][ni], 0, 0, 0);
    __syncthreads();
  }
  #pragma unroll
  for (int ni = 0; ni < 4; ++ni) {
    int col = bn + wc * 64 + ni * 16 + (lane & 15);
    float bv = bias[col];
    #pragma unroll
    for (int mi = 0; mi < 4; ++mi) {
      #pragma unroll
      for (int j = 0; j < 4; ++j) {
        int row = bm + wr * 64 + mi * 16 + (lane >> 4) * 4 + j;
        C[(size_t)row * N + col] = f2bf(acc[mi][ni][j] + bv);
      }
    }
  }
}

// ---------------- fused retrieval v4: async swizzled LDS staging, 1 barrier/chunk ----------
// grid: 782 x 256. Block covers 64 rows x 32 batches. Chunk = 64 floats/row staged via
// global_load_lds with XOR-swizzled source (16B slot u = ((c&7)^(r&7))|(c&8)); compute
// lane=row reads swizzled -> conflict-free. Double-buffered, one __syncthreads per chunk.
__global__ __launch_bounds__(256, 4) void k_dots(const float* __restrict__ table,
    const float* __restrict__ vecs, float* __restrict__ norm2g,
    float* __restrict__ candv, int* __restrict__ candi, int pass1, float eps) {
  __shared__ float t_lds[2][64 * 64];   // 2 x 16KB
  __shared__ float norm_lds[64];
  __shared__ float iv_lds[64];
  float* dot_lds = &t_lds[0][0];        // aliased [32][66] after main loop (8.4KB < 16KB)

  int tid = threadIdx.x;
  int wave = tid >> 6, lane = tid & 63;
  int rbase = blockIdx.x * 64;

  int b0 = __builtin_amdgcn_readfirstlane(wave * 8);
  const float* qb = vecs + (size_t)b0 * DMODEL;

  int u = lane & 15;
  int rsub = lane >> 4;      // 0..3 within 4-row group

  float acc[8] = {0.f,0.f,0.f,0.f,0.f,0.f,0.f,0.f};
  float accn = 0.f;

  // stage chunk `k0` into buffer `buf`: wave stages its 16 rows in 4 instrs
  auto STAGE = [&](int buf, int k0) {
    #pragma unroll
    for (int j = 0; j < 4; ++j) {
      int rl = wave * 16 + j * 4 + rsub;          // local row this lane feeds
      int gr = rbase + rl; if (gr >= NROWS) gr = NROWS - 1;
      int c = ((u & 7) ^ (rl & 7)) | (u & 8);     // pre-swizzled source slot
      gl_lds16(table + (size_t)gr * DMODEL + k0 + c * 4,
               &t_lds[buf][(wave * 16 + j * 4) * 64]);
    }
  };

  STAGE(0, 0);
  __syncthreads();
  int cur = 0;
  for (int ch = 0; ch < NCHUNK; ++ch) {
    int k0 = ch * CHUNKF;
    if (ch + 1 < NCHUNK) STAGE(cur ^ 1, k0 + CHUNKF);
    #pragma unroll 2
    for (int q4 = 0; q4 < 16; ++q4) {
      int uu = ((q4 & 7) ^ (lane & 7)) | (q4 & 8);
      float4 tv = *(const float4*)(&t_lds[cur][lane * 64 + uu * 4]);
      if (pass1 && wave == 0)
        accn += tv.x * tv.x + tv.y * tv.y + tv.z * tv.z + tv.w * tv.w;
      #pragma unroll
      for (int j = 0; j < 8; ++j) {
        float4 qv = *(const float4*)(qb + (size_t)j * DMODEL + k0 + q4 * 4);
        acc[j] += tv.x * qv.x + tv.y * qv.y + tv.z * qv.z + tv.w * qv.w;
      }
    }
    __syncthreads();   // drains staged loads; separates buffers
    cur ^= 1;
  }

  // write dots (aliased LDS) + norms
  #pragma unroll
  for (int j = 0; j < 8; ++j) dot_lds[(wave * 8 + j) * 66 + lane] = acc[j];
  if (wave == 0) {
    norm_lds[lane] = accn;
    if (pass1) {
      int rw = rbase + lane;
      if (rw < NROWS) norm2g[rw] = accn;
    }
  }
  __syncthreads();
  if (tid < 64) {
    int rc = rbase + tid;
    if (rc >= NROWS) rc = NROWS - 1;
    float n2 = pass1 ? norm_lds[tid] : norm2g[rc];
    iv_lds[tid] = 1.0f / fmaxf(sqrtf(n2), eps);
  }
  __syncthreads();

  if (tid < 32) {
    float tv[5]; int ti[5];
    #pragma unroll
    for (int j = 0; j < 5; ++j) { tv[j] = -3.4e38f; ti[j] = 0x7fffffff; }
    for (int r = 0; r < 64; ++r) {
      int rw = rbase + r;
      if (rw >= NROWS) break;
      float v = dot_lds[tid * 66 + r] * iv_lds[r];
      if (v > tv[4] || (v == tv[4] && rw < ti[4])) {
        tv[4] = v; ti[4] = rw;
        #pragma unroll
        for (int j = 4; j > 0; --j) {
          bool sw = (tv[j] > tv[j-1]) || (tv[j] == tv[j-1] && ti[j] < ti[j-1]);
          if (sw) {
            float fv = tv[j]; tv[j] = tv[j-1]; tv[j-1] = fv;
            int ivx = ti[j]; ti[j] = ti[j-1]; ti[j-1] = ivx;
          }
        }
      }
    }
    #pragma unroll
    for (int j = 0; j < 5; ++j) {
      candv[((size_t)blockIdx.x * 32 + tid) * 5 + j] = tv[j];
      candi[((size_t)blockIdx.x * 32 + tid) * 5 + j] = ti[j];
    }
  }
}

// ---------------- merge per-block candidates -> global top-K per batch ----------------
__global__ void k_merge(const float* __restrict__ candv, const int* __restrict__ candi,
                        int* __restrict__ out_idx, int K, int nblk) {
  int b = blockIdx.x;
  int tid = threadIdx.x; // 256
  float tv[5]; int ti[5];
  #pragma unroll
  for (int j = 0; j < 5; ++j) { tv[j] = -3.4e38f; ti[j] = 0x7fffffff; }
  for (int blk = tid; blk < nblk; blk += 256) {
    #pragma unroll
    for (int j = 0; j < 5; ++j) {
      float v = candv[((size_t)blk * 32 + b) * 5 + j];
      int idx = candi[((size_t)blk * 32 + b) * 5 + j];
      if (v > tv[4] || (v == tv[4] && idx < ti[4])) {
        tv[4] = v; ti[4] = idx;
        #pragma unroll
        for (int jj = 4; jj > 0; --jj) {
          bool sw = (tv[jj] > tv[jj-1]) || (tv[jj] == tv[jj-1] && ti[jj] < ti[jj-1]);
          if (sw) {
            float fv = tv[jj]; tv[jj] = tv[jj-1]; tv[jj-1] = fv;
            int ivx = ti[jj]; ti[jj] = ti[jj-1]; ti[jj-1] = ivx;
          }
        }
      }
    }
  }
  __shared__ float lv[256 * 5];
  __shared__ int   li[256 * 5];
  #pragma unroll
  for (int j = 0; j < 5; ++j) { lv[tid * 5 + j] = tv[j]; li[tid * 5 + j] = ti[j]; }
  __syncthreads();
  for (int off = 128; off >= 1; off >>= 1) {
    if (tid < off) {
      float av[5], bv[5]; int ai[5], bi[5];
      #pragma unroll
      for (int j = 0; j < 5; ++j) {
        av[j] = lv[tid * 5 + j]; ai[j] = li[tid * 5 + j];
        bv[j] = lv[(tid + off) * 5 + j]; bi[j] = li[(tid + off) * 5 + j];
      }
      int pa = 0, pb = 0;
      float mv[5]; int mi[5];
      #pragma unroll
      for (int j = 0; j < 5; ++j) {
        bool ta = (av[pa] > bv[pb]) || (av[pa] == bv[pb] && ai[pa] < bi[pb]);
        if (ta) { mv[j] = av[pa]; mi[j] = ai[pa]; ++pa; }
        else    { mv[j] = bv[pb]; mi[j] = bi[pb]; ++pb; }
      }
      #pragma unroll
      for (int j = 0; j < 5; ++j) { lv[tid * 5 + j] = mv[j]; li[tid * 5 + j] = mi[j]; }
    }
    __syncthreads();
  }
  if (tid == 0) {
    for (int j = 0; j < K; ++j) out_idx[b * K + j] = li[j];
  }
}

// ---------------- gathers ----------------
__global__ void k_gather_sel(const float* __restrict__ table, const int* __restrict__ best,
                             float* __restrict__ sel) {
  int b = blockIdx.x, e = threadIdx.x; // 1024
  int idx = best[b];
  sel[b * DMODEL + e] = table[(size_t)idx * DMODEL + e];
}

__global__ void k_gather_targets(const float* __restrict__ table, const int* __restrict__ idx5,
                                 float* __restrict__ tg) {
  int bt = blockIdx.x, e = threadIdx.x; // 1024
  int idx = idx5[bt];
  tg[(size_t)bt * DMODEL + e] = table[(size_t)idx * DMODEL + e];
}

// ---------------- attention: one block per (b, t) ----------------
__global__ __launch_bounds__(256) void k_attention(const float* __restrict__ q,
    const unsigned short* __restrict__ kb, const unsigned short* __restrict__ vb,
    float* __restrict__ obuf) {
  int bt = blockIdx.x;
  int b = bt / NTOPK;
  int tid = threadIdx.x; // 256
  __shared__ float q_l[DMODEL];
  __shared__ float sc[4][SEQ];
  #pragma unroll
  for (int j = 0; j < 4; ++j) q_l[tid + 256 * j] = q[(size_t)bt * DMODEL + tid + 256 * j];
  __syncthreads();
  { // scores: thread = key position s
    int s = tid;
    const unsigned short* krow = kb + ((size_t)(b * SEQ + s)) * DMODEL;
    #pragma unroll
    for (int h = 0; h < 4; ++h) {
      float d = 0.f;
      for (int dd = 0; dd < 256; dd += 8) {
        uint4 pk = *(const uint4*)(krow + h * 256 + dd);
        const unsigned short* ph = (const unsigned short*)&pk;
        #pragma unroll
        for (int j2 = 0; j2 < 8; ++j2) d += bf2f(ph[j2]) * q_l[h * 256 + dd + j2];
      }
      sc[h][s] = d * 0.0625f; // 1/sqrt(256)
    }
  }
  __syncthreads();
  { // softmax: wave w handles head h=w
    int h = tid >> 6, lane = tid & 63;
    float vals[4];
    float mx = -3.4e38f;
    #pragma unroll
    for (int j = 0; j < 4; ++j) { vals[j] = sc[h][lane + 64 * j]; mx = fmaxf(mx, vals[j]); }
    #pragma unroll
    for (int o = 1; o < 64; o <<= 1) mx = fmaxf(mx, __shfl_xor(mx, o));
    float sum = 0.f;
    #pragma unroll
    for (int j = 0; j < 4; ++j) { vals[j] = expf(vals[j] - mx); sum += vals[j]; }
    #pragma unroll
    for (int o = 1; o < 64; o <<= 1) sum += __shfl_xor(sum, o);
    float rz = 1.0f / sum;
    #pragma unroll
    for (int j = 0; j < 4; ++j) sc[h][lane + 64 * j] = vals[j] * rz;
  }
  __syncthreads();
  { // PV: thread owns 4 contiguous output dims
    int h = tid >> 6;
    int e0 = tid * 4;
    float a0 = 0.f, a1 = 0.f, a2 = 0.f, a3 = 0.f;
    const unsigned short* vbase = vb + (size_t)(b * SEQ) * DMODEL + e0;
    for (int s = 0; s < SEQ; ++s) {
      float w = sc[h][s];
      ushort4 v4 = *(const ushort4*)(vbase + (size_t)s * DMODEL);
      a0 += w * bf2f(v4.x); a1 += w * bf2f(v4.y); a2 += w * bf2f(v4.z); a3 += w * bf2f(v4.w);
    }
    float* op = obuf + (size_t)bt * DMODEL + e0;
    op[0] = a0; op[1] = a1; op[2] = a2; op[3] = a3;
  }
}

// ---------------- sum over the 5 queries ----------------
__global__ void k_osum(const float* __restrict__ obuf, float* __restrict__ osum) {
  int g = blockIdx.x * blockDim.x + threadIdx.x; // 32768
  if (g >= BATCH * DMODEL) return;
  int b = g >> 10, e = g & 1023;
  float s = 0.f;
  #pragma unroll
  for (int t = 0; t < NTOPK; ++t) s += obuf[(size_t)(b * NTOPK + t) * DMODEL + e];
  osum[g] = s;
}

extern "C" void kernel_launch(void* const* d_in, const int* in_sizes, int n_in,
                              void* d_out, int out_size, void* d_ws, size_t ws_size,
                              hipStream_t stream) {
  const float* hidden = (const float*)d_in[0];
  const float* table  = (const float*)d_in[1];
  const float* fc1_w  = (const float*)d_in[2];
  const float* fc1_b  = (const float*)d_in[3];
  const float* q_w    = (const float*)d_in[4];
  const float* q_b    = (const float*)d_in[5];
  const float* k_w    = (const float*)d_in[6];
  const float* k_b    = (const float*)d_in[7];
  const float* v_w    = (const float*)d_in[8];
  const float* v_b    = (const float*)d_in[9];
  const float* out_w  = (const float*)d_in[10];
  const float* out_b  = (const float*)d_in[11];
  float* out = (float*)d_out;

  char* ws = (char*)d_ws;
  size_t off = 0;
  auto alloc = [&](size_t bytes) -> void* {
    void* p = ws + off;
    off += (bytes + 255) & ~(size_t)255;
    return p;
  };
  unsigned short* hid_bf  = (unsigned short*)alloc((size_t)BATCH * SEQ * DIN * 2);
  unsigned short* fc1w_bf = (unsigned short*)alloc((size_t)DMODEL * DIN * 2);
  unsigned short* kw_bf   = (unsigned short*)alloc((size_t)DMODEL * DMODEL * 2);
  unsigned short* vw_bf   = (unsigned short*)alloc((size_t)DMODEL * DMODEL * 2);
  unsigned short* x_bf    = (unsigned short*)alloc((size_t)BATCH * SEQ * DMODEL * 2);
  unsigned short* k_bf    = (unsigned short*)alloc((size_t)BATCH * SEQ * DMODEL * 2);
  unsigned short* v_bf    = (unsigned short*)alloc((size_t)BATCH * SEQ * DMODEL * 2);
  float* hpart   = (float*)alloc((size_t)8 * BATCH * DIN * 4);
  float* hm      = (float*)alloc((size_t)BATCH * DIN * 4);
  float* m       = (float*)alloc((size_t)BATCH * DMODEL * 4);
  float* sel     = (float*)alloc((size_t)BATCH * DMODEL * 4);
  float* norm2   = (float*)alloc((size_t)NROWS * 4);
  float* candv   = (float*)alloc((size_t)DOTS_BLOCKS * 32 * 5 * 4);
  int*   candi   = (int*)alloc((size_t)DOTS_BLOCKS * 32 * 5 * 4);
  int*   best    = (int*)alloc(BATCH * 4);
  int*   idx5    = (int*)alloc(BATCH * NTOPK * 4);
  float* targets = (float*)alloc((size_t)BATCH * NTOPK * DMODEL * 4);
  float* qbuf    = (float*)alloc((size_t)BATCH * NTOPK * DMODEL * 4);
  float* obuf    = (float*)alloc((size_t)BATCH * NTOPK * DMODEL * 4);
  float* osum    = (float*)alloc((size_t)BATCH * DMODEL * 4);
  (void)ws_size; (void)in_sizes; (void)n_in; (void)out_size;

  // converts to bf16
  k_f32_to_bf16<<<2048, 256, 0, stream>>>(hidden, hid_bf, BATCH * SEQ * DIN);
  k_f32_to_bf16_3<<<1024, 256, 0, stream>>>(fc1_w, fc1w_bf, DMODEL * DIN,
                                            k_w, kw_bf, DMODEL * DMODEL,
                                            v_w, vw_bf, DMODEL * DMODEL);

  // exact-fp32 mean path: m = mean_s(hidden) @ fc1_w^T + fc1_b
  k_mean_part<<<256, 768, 0, stream>>>(hidden, hpart);
  k_mean_reduce<<<32, 768, 0, stream>>>(hpart, hm);
  k_sgemm_wt<<<dim3(16, 1), 256, 0, stream>>>(hm, fc1_w, fc1_b, m, 32, DMODEL, DIN, 1.0f);

  // fc1: x (bf16)
  k_bf16_gemm<<<dim3(8, 64), 256, 0, stream>>>(hid_bf, fc1w_bf, fc1_b, x_bf, BATCH * SEQ, DMODEL, DIN);

  // retrieval pass 1: cos argmax
  k_dots<<<DOTS_BLOCKS, 256, 0, stream>>>(table, m, norm2, candv, candi, 1, 1e-6f);
  k_merge<<<32, 256, 0, stream>>>(candv, candi, best, 1, DOTS_BLOCKS);
  k_gather_sel<<<32, 1024, 0, stream>>>(table, best, sel);

  // retrieval pass 2: top-5 by dot(sel, t_i)/||t_i|| (ranking-equivalent to ref d2)
  k_dots<<<DOTS_BLOCKS, 256, 0, stream>>>(table, sel, norm2, candv, candi, 0, 1e-12f);
  k_merge<<<32, 256, 0, stream>>>(candv, candi, idx5, NTOPK, DOTS_BLOCKS);
  k_gather_targets<<<160, 1024, 0, stream>>>(table, idx5, targets);

  // q projection (fp32, small M)
  k_sgemm_wt<<<dim3(16, 5), 256, 0, stream>>>(targets, q_w, q_b, qbuf, BATCH * NTOPK, DMODEL, DMODEL, 1.0f);

  // k, v projections (bf16 MFMA)
  k_bf16_gemm<<<dim3(8, 64), 256, 0, stream>>>(x_bf, kw_bf, k_b, k_bf, BATCH * SEQ, DMODEL, DMODEL);
  k_bf16_gemm<<<dim3(8, 64), 256, 0, stream>>>(x_bf, vw_bf, v_b, v_bf, BATCH * SEQ, DMODEL, DMODEL);

  // attention + sum over queries + output projection
  k_attention<<<160, 256, 0, stream>>>(qbuf, k_bf, v_bf, obuf);
  k_osum<<<128, 256, 0, stream>>>(obuf, osum);
  k_sgemm_wt<<<dim3(16, 1), 256, 0, stream>>>(osum, out_w, out_b, out, 32, DMODEL, DMODEL, 5.0f);
}